// Round 1
// baseline (137.124 us; speedup 1.0000x reference)
//
#include <hip/hip_runtime.h>

#define NCH 4            // channels per block
#define XRS 36           // LDS x row stride (floats) — 16B aligned, odd-ish bank pattern via batch stride
#define XBS (29 * XRS)   // 1044 floats per batch image (29 rows: input rows -1..27)

__device__ __forceinline__ float sgnf(float v) {
    return (v > 0.f) ? 1.f : ((v < 0.f) ? -1.f : 0.f);
}

// ---------------------------------------------------------------------------
// Main kernel: one block handles NCH consecutive channels end-to-end.
// ---------------------------------------------------------------------------
__global__ __launch_bounds__(256, 2) void hdc_main(
    const float* __restrict__ x,
    const float* __restrict__ W1, const float* __restrict__ b1,
    const float* __restrict__ g1, const float* __restrict__ be1,
    const float* __restrict__ W2, const float* __restrict__ b2,
    const float* __restrict__ g2, const float* __restrict__ be2,
    const float* __restrict__ W3, const float* __restrict__ b3,
    const float* __restrict__ g3, const float* __restrict__ be3,
    const float* __restrict__ Wc, float* __restrict__ out)
{
    __shared__ __align__(16) float xs[16 * XBS];     // 66816 B padded input
    __shared__ signed char h1s[NCH * 2704];          // 10816 B binarized conv1
    __shared__ float w1s[NCH * 25];                  // sign(W1) per channel
    __shared__ float redbuf[4][4];                   // per-wave partials
    __shared__ float stats[NCH][2];                  // mean, invstd per channel
    __shared__ float h3buf[NCH * 16];                // final per-(ch,b) signs

    const int tid  = threadIdx.x;
    const int base = blockIdx.x * NCH;

    // ---- stage x into LDS with 1-pixel zero pad on top/left (rows/cols -1) ----
    for (int i = tid; i < 16 * 841; i += 256) {       // 841 = 29*29 valid floats
        int b_  = i / 841;
        int rem = i - b_ * 841;
        int r_  = rem / 29, c_ = rem - r_ * 29;
        float v = 0.f;
        if (r_ >= 1 && c_ >= 1) v = x[b_ * 784 + (r_ - 1) * 28 + (c_ - 1)];
        xs[b_ * XBS + r_ * XRS + c_] = v;
    }
    for (int i = tid; i < NCH * 25; i += 256)
        w1s[i] = sgnf(W1[base * 25 + i]);
    __syncthreads();

    // strip mapping: thread -> (oy, batch); 208 active threads
    const bool act = (tid < 208);
    const int oy = tid >> 4;          // 0..12
    const int bb = tid & 15;          // 0..15
    const int wv = tid >> 6;
    const int ln = tid & 63;

    // ---- conv1 + BN1 + binarize, 2 channels at a time ----
    for (int p = 0; p < NCH / 2; ++p) {
        const int d0 = base + 2 * p, d1 = d0 + 1;
        float wa[25], wb[25];
        #pragma unroll
        for (int k = 0; k < 25; ++k) {
            wa[k] = w1s[(2 * p) * 25 + k];
            wb[k] = w1s[(2 * p + 1) * 25 + k];
        }
        const float b1a = b1[d0], b1b = b1[d1];
        float fa[13], fb[13];
        #pragma unroll
        for (int i = 0; i < 13; ++i) { fa[i] = b1a; fb[i] = b1b; }

        if (act) {
            #pragma unroll
            for (int ky = 0; ky < 5; ++ky) {
                // input row (2*oy - 1 + ky) stored at row index (2*oy + ky)
                const float* rp = &xs[bb * XBS + (2 * oy + ky) * XRS];
                float r[29];
                #pragma unroll
                for (int j = 0; j < 29; ++j) r[j] = rp[j];
                #pragma unroll
                for (int kx = 0; kx < 5; ++kx) {
                    const float wka = wa[5 * ky + kx], wkb = wb[5 * ky + kx];
                    #pragma unroll
                    for (int ox = 0; ox < 13; ++ox) {
                        const float xv = r[2 * ox + kx];
                        fa[ox] = fmaf(xv, wka, fa[ox]);
                        fb[ox] = fmaf(xv, wkb, fb[ox]);
                    }
                }
            }
        }

        // pass 1: means
        float sa = 0.f, sb = 0.f;
        if (act) {
            #pragma unroll
            for (int i = 0; i < 13; ++i) { sa += fa[i]; sb += fb[i]; }
        }
        #pragma unroll
        for (int m = 32; m >= 1; m >>= 1) {
            sa += __shfl_xor(sa, m, 64);
            sb += __shfl_xor(sb, m, 64);
        }
        if (ln == 0) { redbuf[wv][0] = sa; redbuf[wv][1] = sb; }
        __syncthreads();
        if (tid == 0) {
            float ta = redbuf[0][0] + redbuf[1][0] + redbuf[2][0] + redbuf[3][0];
            float tb = redbuf[0][1] + redbuf[1][1] + redbuf[2][1] + redbuf[3][1];
            stats[2 * p][0]     = ta / 2704.f;
            stats[2 * p + 1][0] = tb / 2704.f;
        }
        __syncthreads();
        const float mua = stats[2 * p][0], mub = stats[2 * p + 1][0];

        // pass 2: variances (two-pass to mirror jnp.var)
        float da = 0.f, db = 0.f;
        if (act) {
            #pragma unroll
            for (int i = 0; i < 13; ++i) {
                const float ea = fa[i] - mua, eb = fb[i] - mub;
                da = fmaf(ea, ea, da);
                db = fmaf(eb, eb, db);
            }
        }
        #pragma unroll
        for (int m = 32; m >= 1; m >>= 1) {
            da += __shfl_xor(da, m, 64);
            db += __shfl_xor(db, m, 64);
        }
        if (ln == 0) { redbuf[wv][2] = da; redbuf[wv][3] = db; }
        __syncthreads();
        if (tid == 0) {
            float ta = redbuf[0][2] + redbuf[1][2] + redbuf[2][2] + redbuf[3][2];
            float tb = redbuf[0][3] + redbuf[1][3] + redbuf[2][3] + redbuf[3][3];
            stats[2 * p][1]     = rsqrtf(ta / 2704.f + 1e-5f);
            stats[2 * p + 1][1] = rsqrtf(tb / 2704.f + 1e-5f);
        }
        __syncthreads();

        if (act) {
            const float iva = stats[2 * p][1], ivb = stats[2 * p + 1][1];
            const float ga = g1[d0], gb = g1[d1];
            const float bea = be1[d0], beb = be1[d1];
            signed char* ha = &h1s[(2 * p) * 2704 + bb * 169 + oy * 13];
            signed char* hb = &h1s[(2 * p + 1) * 2704 + bb * 169 + oy * 13];
            #pragma unroll
            for (int i = 0; i < 13; ++i) {
                const float xna = (fa[i] - mua) * iva;
                const float ya  = fmaf(xna, ga, bea);
                const float za  = ((ya > 0.f) ? ya : 0.01f * ya) - 0.5f;
                ha[i] = (za > 0.f) ? 1 : ((za < 0.f) ? -1 : 0);
                const float xnb = (fb[i] - mub) * ivb;
                const float yb  = fmaf(xnb, gb, beb);
                const float zb  = ((yb > 0.f) ? yb : 0.01f * yb) - 0.5f;
                hb[i] = (zb > 0.f) ? 1 : ((zb < 0.f) ? -1 : 0);
            }
        }
    }
    __syncthreads();

    // ---- conv2 (exact int) + BN2 + sign + conv3 + BN3 + sign: 64 threads ----
    if (tid < NCH * 16) {
        const int ch = tid >> 4, b_ = tid & 15;
        const int d = base + ch;
        float sw2[9];
        #pragma unroll
        for (int k = 0; k < 9; ++k) sw2[k] = sgnf(W2[d * 9 + k]);
        const float b2v = b2[d];
        const signed char* hp = &h1s[ch * 2704 + b_ * 169];

        float c2[36];
        #pragma unroll
        for (int oy2 = 0; oy2 < 6; ++oy2) {
            float rr[3][13];
            #pragma unroll
            for (int ky = 0; ky < 3; ++ky)
                #pragma unroll
                for (int j = 0; j < 13; ++j)
                    rr[ky][j] = (float)hp[(2 * oy2 + ky) * 13 + j];
            #pragma unroll
            for (int ox2 = 0; ox2 < 6; ++ox2) {
                float s = b2v;
                #pragma unroll
                for (int ky = 0; ky < 3; ++ky)
                    #pragma unroll
                    for (int kx = 0; kx < 3; ++kx)
                        s = fmaf(rr[ky][2 * ox2 + kx], sw2[3 * ky + kx], s);
                c2[oy2 * 6 + ox2] = s;
            }
        }

        // BN2 over (b, 6, 6): values are exact small integers -> exact sums
        float s2 = 0.f;
        #pragma unroll
        for (int i = 0; i < 36; ++i) s2 += c2[i];
        #pragma unroll
        for (int m = 8; m >= 1; m >>= 1) s2 += __shfl_xor(s2, m, 16);
        const float mu2 = s2 / 576.f;
        float d2 = 0.f;
        #pragma unroll
        for (int i = 0; i < 36; ++i) { const float e = c2[i] - mu2; d2 = fmaf(e, e, d2); }
        #pragma unroll
        for (int m = 8; m >= 1; m >>= 1) d2 += __shfl_xor(d2, m, 16);
        const float inv2 = rsqrtf(d2 / 576.f + 1e-5f);
        const float g2v = g2[d], be2v = be2[d];

        // binarize h2 fused into conv3
        float z3 = b3[d];
        #pragma unroll
        for (int i = 0; i < 36; ++i) {
            const float xn = (c2[i] - mu2) * inv2;
            const float y  = fmaf(xn, g2v, be2v);
            const float z  = ((y > 0.f) ? y : 0.01f * y) - 0.5f;
            const float h2 = (z > 0.f) ? 1.f : ((z < 0.f) ? -1.f : 0.f);
            z3 = fmaf(h2, W3[d * 36 + i], z3);
        }

        // BN3 over batch (16 lanes)
        float s3 = z3;
        #pragma unroll
        for (int m = 8; m >= 1; m >>= 1) s3 += __shfl_xor(s3, m, 16);
        const float mu3 = s3 / 16.f;
        const float e3 = z3 - mu3;
        float d3 = e3 * e3;
        #pragma unroll
        for (int m = 8; m >= 1; m >>= 1) d3 += __shfl_xor(d3, m, 16);
        const float inv3 = rsqrtf(d3 / 16.f + 1e-5f);
        const float xn3 = (z3 - mu3) * inv3;
        const float y3  = fmaf(xn3, g3[d], be3[d]);
        const float zz  = ((y3 > 0.f) ? y3 : 0.01f * y3) - 0.5f;
        h3buf[tid] = (zz > 0.f) ? 1.f : ((zz < 0.f) ? -1.f : 0.f);
    }
    __syncthreads();

    // ---- per-block class partials: exact-integer atomic accumulation ----
    if (tid < 160) {
        const int b_ = tid / 10, c_ = tid - b_ * 10;
        float s = 0.f;
        #pragma unroll
        for (int ch = 0; ch < NCH; ++ch)
            s += h3buf[ch * 16 + b_] * sgnf(Wc[c_ * 10000 + base + ch]);
        atomicAdd(&out[b_ * 10 + c_], s);
    }
}

// ---------------------------------------------------------------------------
// Final scale: sims / sqrt(10000) == sims / 100.0f (exact match to reference)
// ---------------------------------------------------------------------------
__global__ void hdc_scale(float* __restrict__ out) {
    const int i = threadIdx.x;
    if (i < 160) out[i] = out[i] / 100.0f;
}

extern "C" void kernel_launch(void* const* d_in, const int* in_sizes, int n_in,
                              void* d_out, int out_size, void* d_ws, size_t ws_size,
                              hipStream_t stream) {
    const float* x   = (const float*)d_in[0];
    const float* W1  = (const float*)d_in[1];
    const float* b1  = (const float*)d_in[2];
    const float* g1  = (const float*)d_in[3];
    const float* be1 = (const float*)d_in[4];
    const float* W2  = (const float*)d_in[5];
    const float* b2  = (const float*)d_in[6];
    const float* g2  = (const float*)d_in[7];
    const float* be2 = (const float*)d_in[8];
    const float* W3  = (const float*)d_in[9];
    const float* b3  = (const float*)d_in[10];
    const float* g3  = (const float*)d_in[11];
    const float* be3 = (const float*)d_in[12];
    const float* Wc  = (const float*)d_in[13];
    float* out = (float*)d_out;

    hipMemsetAsync(out, 0, 160 * sizeof(float), stream);
    hdc_main<<<dim3(10000 / NCH), dim3(256), 0, stream>>>(
        x, W1, b1, g1, be1, W2, b2, g2, be2, W3, b3, g3, be3, Wc, out);
    hdc_scale<<<dim3(1), dim3(192), 0, stream>>>(out);
}